// Round 1
// baseline (867.472 us; speedup 1.0000x reference)
//
#include <hip/hip_runtime.h>

#define TTL 512
#define NB  128
#define PAD 128
#define ASP 8
#define DD  256
#define HID 1024            // BERT * NL
#define ROWS9 (TTL * 9)     // 4608 rows per side (8 asp + 1 sum)

typedef float4 f4;

__device__ __forceinline__ float blockReduceSum(float v, float* red) {
    int t = threadIdx.x;
    red[t] = v;
    __syncthreads();
    #pragma unroll
    for (int s = 128; s > 0; s >>= 1) {
        if (t < s) red[t] += red[t + s];
        __syncthreads();
    }
    float r = red[0];
    __syncthreads();
    return r;
}

// ---------------- K1: contract hidden over PAD axis ----------------
// Hcat[side][r*9+a][k] : a<8 -> sum_p loc[r,a,p]*hidden[r,p,k] ; a=8 -> sum_p hidden
// Mult[side][r*9+a]    : a<8 -> sum_p loc[r,a,p] ; a=8 -> 128
__global__ __launch_bounds__(256) void k_reduce(
    const float* __restrict__ uh, const float* __restrict__ ih,
    const float* __restrict__ uloc, const float* __restrict__ iloc,
    float* __restrict__ Hcat, float* __restrict__ Mult)
{
    const int r = blockIdx.x;
    const int side = blockIdx.y;
    const float* h   = side ? ih   : uh;
    const float* loc = side ? iloc : uloc;
    __shared__ float locT[PAD][ASP];
    const int t = threadIdx.x;

    for (int i = t; i < ASP * PAD; i += 256) {
        int a = i >> 7, p = i & 127;
        locT[p][a] = loc[r * ASP * PAD + i];
    }
    __syncthreads();

    float* mult = Mult + (size_t)side * ROWS9 + r * 9;
    if (t < ASP) {
        float s = 0.f;
        for (int p = 0; p < PAD; p++) s += locT[p][t];
        mult[t] = s;
    } else if (t == ASP) {
        mult[8] = 128.0f;
    }

    const f4* h4 = (const f4*)(h + (size_t)r * PAD * HID);
    f4 acc[9];
    #pragma unroll
    for (int a = 0; a < 9; a++) acc[a] = make_float4(0.f, 0.f, 0.f, 0.f);

    for (int p = 0; p < PAD; p++) {
        f4 v = h4[p * (HID / 4) + t];
        const f4* lrow = (const f4*)locT[p];
        f4 w0 = lrow[0], w1 = lrow[1];
        acc[8].x += v.x; acc[8].y += v.y; acc[8].z += v.z; acc[8].w += v.w;
        #define FMA_A(ai, ws) { acc[ai].x += (ws)*v.x; acc[ai].y += (ws)*v.y; \
                                acc[ai].z += (ws)*v.z; acc[ai].w += (ws)*v.w; }
        FMA_A(0, w0.x) FMA_A(1, w0.y) FMA_A(2, w0.z) FMA_A(3, w0.w)
        FMA_A(4, w1.x) FMA_A(5, w1.y) FMA_A(6, w1.z) FMA_A(7, w1.w)
        #undef FMA_A
    }

    f4* out = (f4*)(Hcat + ((size_t)side * ROWS9 + (size_t)r * 9) * HID);
    #pragma unroll
    for (int a = 0; a < 9; a++) out[a * (HID / 4) + t] = acc[a];
}

// ---------------- K2: fp32 tiled GEMM  C[m,n] = A[m,:K] @ B[:K,n] (+ mult[m]*bias[n]) ---
#define BM 64
#define BN 64
#define BKK 32
__global__ __launch_bounds__(256) void k_gemm(
    const float* __restrict__ A, const float* __restrict__ B,
    const float* __restrict__ bias, const float* __restrict__ mult,
    float* __restrict__ C, int M, int N, int K)
{
    __shared__ float As[BKK][BM];
    __shared__ float Bs[BKK][BN];
    const int t = threadIdx.x;
    const int m0 = blockIdx.x * BM, n0 = blockIdx.y * BN;
    const int tm = (t >> 4) << 2;   // 0..60
    const int tn = (t & 15) << 2;   // 0..60
    float c[4][4] = {};

    for (int k0 = 0; k0 < K; k0 += BKK) {
        #pragma unroll
        for (int i = 0; i < 2; i++) {
            int e = t + i * 256;
            int row = e >> 3;            // 8 f4 per 32-wide k row
            int kq = (e & 7) << 2;
            f4 v = *(const f4*)&A[(size_t)(m0 + row) * K + k0 + kq];
            As[kq + 0][row] = v.x; As[kq + 1][row] = v.y;
            As[kq + 2][row] = v.z; As[kq + 3][row] = v.w;
        }
        #pragma unroll
        for (int i = 0; i < 2; i++) {
            int e = t + i * 256;
            int row = e >> 4;            // 16 f4 per 64-wide n row
            int dq = (e & 15) << 2;
            *(f4*)&Bs[row][dq] = *(const f4*)&B[(size_t)(k0 + row) * N + n0 + dq];
        }
        __syncthreads();
        #pragma unroll
        for (int k = 0; k < BKK; k++) {
            f4 a4 = *(const f4*)&As[k][tm];
            f4 b4 = *(const f4*)&Bs[k][tn];
            c[0][0] += a4.x * b4.x; c[0][1] += a4.x * b4.y; c[0][2] += a4.x * b4.z; c[0][3] += a4.x * b4.w;
            c[1][0] += a4.y * b4.x; c[1][1] += a4.y * b4.y; c[1][2] += a4.y * b4.z; c[1][3] += a4.y * b4.w;
            c[2][0] += a4.z * b4.x; c[2][1] += a4.z * b4.y; c[2][2] += a4.z * b4.z; c[2][3] += a4.z * b4.w;
            c[3][0] += a4.w * b4.x; c[3][1] += a4.w * b4.y; c[3][2] += a4.w * b4.z; c[3][3] += a4.w * b4.w;
        }
        __syncthreads();
    }

    #pragma unroll
    for (int i = 0; i < 4; i++) {
        int m = m0 + tm + i;
        f4 v = make_float4(c[i][0], c[i][1], c[i][2], c[i][3]);
        if (mult) {
            float mm = mult[m];
            v.x += mm * bias[n0 + tn + 0];
            v.y += mm * bias[n0 + tn + 1];
            v.z += mm * bias[n0 + tn + 2];
            v.w += mm * bias[n0 + tn + 3];
        }
        *(f4*)&C[(size_t)m * N + n0 + tn] = v;
    }
}

// ---------------- K0: ea[side][a] = emb_aspect[a,:] . w_ex[side][256:512] -------------
__global__ __launch_bounds__(256) void k_ea(
    const float* __restrict__ emb, const float* __restrict__ wexu,
    const float* __restrict__ wexi, float* __restrict__ ea)
{
    int a = blockIdx.x, side = blockIdx.y;
    const float* w = (side ? wexi : wexu) + DD;
    __shared__ float red[256];
    float v = emb[a * DD + threadIdx.x] * w[threadIdx.x];
    float s = blockReduceSum(v, red);
    if (threadIdx.x == 0) ea[side * ASP + a] = s;
}

// ---------------- K3: attention scores ------------------------------------------------
__global__ __launch_bounds__(256) void k_scores(
    const float* __restrict__ AspAvg, const float* __restrict__ ClsRepr,
    const float* __restrict__ wexu, const float* __restrict__ wexi,
    const float* __restrict__ wimu, const float* __restrict__ wimi,
    const float* __restrict__ ea,
    float* __restrict__ sc_ex, float* __restrict__ sc_im)
{
    const int r = blockIdx.x, side = blockIdx.y, t = threadIdx.x;
    const float* wex = side ? wexi : wexu;
    const float* wim = side ? wimi : wimu;
    const float* rowbase = AspAvg + ((size_t)side * ROWS9 + (size_t)r * 9) * DD;
    __shared__ float red[256];
    for (int a = 0; a < 8; a++) {
        float v = rowbase[a * DD + t] * wex[t];
        float s = blockReduceSum(v, red);
        if (t == 0) sc_ex[(side * TTL + r) * ASP + a] = tanhf(s + ea[side * ASP + a]);
    }
    float v = ClsRepr[((size_t)side * TTL + r) * DD + t] * wim[t]
            + (rowbase[8 * DD + t] * (1.0f / 128.0f)) * wim[DD + t];
    float s = blockReduceSum(v, red);
    if (t == 0) sc_im[side * TTL + r] = tanhf(s);
}

// ---------------- K4: segment softmax attention ---------------------------------------
__global__ __launch_bounds__(256) void k_segattn(
    const float* __restrict__ AspAvg, const float* __restrict__ ClsRepr,
    const float* __restrict__ sc_ex, const float* __restrict__ sc_im,
    const int* __restrict__ useg, const int* __restrict__ iseg,
    float* __restrict__ Expl, float* __restrict__ Impl)
{
    const int b = blockIdx.x, side = blockIdx.y, t = threadIdx.x;
    const int* seg = side ? iseg : useg;
    int lo = 0, hi = TTL;
    while (lo < hi) { int mid = (lo + hi) >> 1; if (seg[mid] < b) lo = mid + 1; else hi = mid; }
    const int start = lo;
    hi = TTL;
    while (lo < hi) { int mid = (lo + hi) >> 1; if (seg[mid] <= b) lo = mid + 1; else hi = mid; }
    const int end = lo;

    const float* scx = sc_ex + side * TTL * ASP;
    for (int a = 0; a < 8; a++) {
        float m = -1e30f;
        for (int r = start; r < end; r++) m = fmaxf(m, scx[r * ASP + a]);
        float den = 0.f;
        for (int r = start; r < end; r++) den += expf(scx[r * ASP + a] - m);
        float acc = 0.f;
        for (int r = start; r < end; r++) {
            float w = expf(scx[r * ASP + a] - m) / den;
            acc += w * AspAvg[((size_t)side * ROWS9 + (size_t)r * 9 + a) * DD + t];
        }
        Expl[(((size_t)side * NB + b) * ASP + a) * DD + t] = acc;
    }
    {
        const float* sci = sc_im + side * TTL;
        float m = -1e30f;
        for (int r = start; r < end; r++) m = fmaxf(m, sci[r]);
        float den = 0.f;
        for (int r = start; r < end; r++) den += expf(sci[r] - m);
        float a1 = 0.f, a2 = 0.f;
        for (int r = start; r < end; r++) {
            float w = expf(sci[r] - m) / den;
            a1 += w * ClsRepr[((size_t)side * TTL + r) * DD + t];
            a2 += w * (AspAvg[((size_t)side * ROWS9 + (size_t)r * 9 + 8) * DD + t] * (1.0f / 128.0f));
        }
        Impl[((size_t)side * NB + b) * (2 * DD) + t] = a1;
        Impl[((size_t)side * NB + b) * (2 * DD) + DD + t] = a2;
    }
}

// ---------------- K5: final heads ------------------------------------------------------
__global__ __launch_bounds__(256) void k_final(
    const float* __restrict__ Expl, const float* __restrict__ Impl,
    const float* __restrict__ imW1, const float* __restrict__ imb1, const float* __restrict__ imW2,
    const float* __restrict__ exW1, const float* __restrict__ exb1, const float* __restrict__ exW2,
    const float* __restrict__ bu, const float* __restrict__ bt, const float* __restrict__ gamma,
    const int* __restrict__ uid, const int* __restrict__ iid, float* __restrict__ out)
{
    const int b = blockIdx.x, t = threadIdx.x;
    __shared__ float catIm[4 * DD];        // 1024 : [u_impl, i_impl]
    __shared__ float catEx[2 * DD][ASP];   // 512 x 8
    __shared__ float red[256];

    catIm[t]       = Impl[(size_t)b * 512 + t];
    catIm[t + 256] = Impl[(size_t)b * 512 + t + 256];
    catIm[t + 512] = Impl[((size_t)NB + b) * 512 + t];
    catIm[t + 768] = Impl[((size_t)NB + b) * 512 + t + 256];
    #pragma unroll
    for (int a = 0; a < 8; a++) {
        catEx[t][a]       = Expl[((size_t)b * ASP + a) * DD + t];
        catEx[t + 256][a] = Expl[(((size_t)NB + b) * ASP + a) * DD + t];
    }
    __syncthreads();

    float g[8];
    #pragma unroll
    for (int a = 0; a < 8; a++) g[a] = gamma[a];

    // implicit head
    float acc = imb1[t];
    for (int k = 0; k < 1024; k++) acc += catIm[k] * imW1[k * DD + t];
    float imh = fmaxf(acc, 0.f);
    float part = imh * imW2[t];

    // explicit head: fold gamma into the d-reduction
    float ex[8];
    #pragma unroll
    for (int a = 0; a < 8; a++) ex[a] = exb1[t];
    for (int k = 0; k < 512; k++) {
        float w = exW1[k * DD + t];
        #pragma unroll
        for (int a = 0; a < 8; a++) ex[a] += catEx[k][a] * w;
    }
    float exs = 0.f;
    #pragma unroll
    for (int a = 0; a < 8; a++) exs += fmaxf(ex[a], 0.f) * g[a];
    part += exs * exW2[t];

    float tot = blockReduceSum(part, red);
    if (t == 0) out[b] = bu[uid[b]] + bt[iid[b]] + tot;
}

// ---------------- launch ---------------------------------------------------------------
extern "C" void kernel_launch(void* const* d_in, const int* in_sizes, int n_in,
                              void* d_out, int out_size, void* d_ws, size_t ws_size,
                              hipStream_t stream) {
    const float* uh    = (const float*)d_in[0];
    const float* ih    = (const float*)d_in[1];
    const float* ucls  = (const float*)d_in[2];
    const float* icls  = (const float*)d_in[3];
    const float* uloc  = (const float*)d_in[4];
    const float* iloc  = (const float*)d_in[5];
    const float* Wuo   = (const float*)d_in[6];
    const float* buo   = (const float*)d_in[7];
    const float* Wio   = (const float*)d_in[8];
    const float* bio   = (const float*)d_in[9];
    const float* emb   = (const float*)d_in[10];
    const float* wexu  = (const float*)d_in[11];
    const float* wexi  = (const float*)d_in[12];
    const float* wimu  = (const float*)d_in[13];
    const float* wimi  = (const float*)d_in[14];
    const float* Wucls = (const float*)d_in[15];
    const float* Wicls = (const float*)d_in[16];
    const float* exW1  = (const float*)d_in[17];
    const float* exb1  = (const float*)d_in[18];
    const float* exW2  = (const float*)d_in[19];
    const float* imW1  = (const float*)d_in[20];
    const float* imb1  = (const float*)d_in[21];
    const float* imW2  = (const float*)d_in[22];
    const float* bu    = (const float*)d_in[23];
    const float* bt    = (const float*)d_in[24];
    const float* gam   = (const float*)d_in[25];
    const int*   useg  = (const int*)d_in[26];
    const int*   iseg  = (const int*)d_in[27];
    const int*   uid   = (const int*)d_in[28];
    const int*   iid   = (const int*)d_in[29];
    float* out = (float*)d_out;

    char* w = (char*)d_ws;
    auto carve = [&](size_t bytes) { void* p = (void*)w; w += (bytes + 255) & ~(size_t)255; return p; };
    float* Hcat    = (float*)carve(2ULL * ROWS9 * HID * 4);      // 37.7 MB
    float* Mult    = (float*)carve(2ULL * ROWS9 * 4);
    float* AspAvg  = (float*)carve(2ULL * ROWS9 * DD * 4);       // 9.4 MB
    float* ClsRepr = (float*)carve(2ULL * TTL * DD * 4);         // 1 MB
    float* sc_ex   = (float*)carve(2ULL * TTL * ASP * 4);
    float* sc_im   = (float*)carve(2ULL * TTL * 4);
    float* ea      = (float*)carve(2ULL * ASP * 4);
    float* Expl    = (float*)carve(2ULL * NB * ASP * DD * 4);    // 2 MB
    float* Impl    = (float*)carve(2ULL * NB * 2 * DD * 4);
    (void)ws_size; (void)n_in; (void)in_sizes; (void)out_size;

    // K1: stream 512 MB of hidden states, contract over PAD
    k_reduce<<<dim3(TTL, 2), 256, 0, stream>>>(uh, ih, uloc, iloc, Hcat, Mult);

    // K2a: asp/avg projection per side: (4608 x 1024) @ (1024 x 256)
    for (int s = 0; s < 2; s++) {
        k_gemm<<<dim3(ROWS9 / BM, DD / BN), 256, 0, stream>>>(
            Hcat + (size_t)s * ROWS9 * HID, s ? Wio : Wuo, s ? bio : buo,
            Mult + (size_t)s * ROWS9, AspAvg + (size_t)s * ROWS9 * DD,
            ROWS9, DD, HID);
    }
    // K2b: cls projection per side: (512 x 256) @ (256 x 256)
    for (int s = 0; s < 2; s++) {
        k_gemm<<<dim3(TTL / BM, DD / BN), 256, 0, stream>>>(
            s ? icls : ucls, s ? Wicls : Wucls, nullptr, nullptr,
            ClsRepr + (size_t)s * TTL * DD, TTL, DD, DD);
    }

    k_ea<<<dim3(ASP, 2), 256, 0, stream>>>(emb, wexu, wexi, ea);
    k_scores<<<dim3(TTL, 2), 256, 0, stream>>>(AspAvg, ClsRepr, wexu, wexi, wimu, wimi, ea, sc_ex, sc_im);
    k_segattn<<<dim3(NB, 2), 256, 0, stream>>>(AspAvg, ClsRepr, sc_ex, sc_im, useg, iseg, Expl, Impl);
    k_final<<<dim3(NB), 256, 0, stream>>>(Expl, Impl, imW1, imb1, imW2,
                                          exW1, exb1, exW2, bu, bt, gam, uid, iid, out);
}

// Round 2
// 776.594 us; speedup vs baseline: 1.1170x; 1.1170x over previous
//
#include <hip/hip_runtime.h>

#define TTL 512
#define NB  128
#define PAD 128
#define ASP 8
#define DD  256
#define HID 1024            // BERT * NL
#define ROWS9 (TTL * 9)     // 4608 rows per side (8 asp + 1 sum)
#define MTOT (2 * ROWS9)    // 9216
#define KS 2                // split-K factor for the big GEMM

typedef float4 f4;

__device__ __forceinline__ float blockReduceSum(float v, float* red) {
    int t = threadIdx.x;
    red[t] = v;
    __syncthreads();
    #pragma unroll
    for (int s = 128; s > 0; s >>= 1) {
        if (t < s) red[t] += red[t + s];
        __syncthreads();
    }
    float r = red[0];
    __syncthreads();
    return r;
}

// ---------------- K1: contract hidden over PAD axis (4-deep pipelined) ----------------
__global__ __launch_bounds__(256) void k_reduce(
    const float* __restrict__ uh, const float* __restrict__ ih,
    const float* __restrict__ uloc, const float* __restrict__ iloc,
    float* __restrict__ Hcat, float* __restrict__ Mult)
{
    const int r = blockIdx.x;
    const int side = blockIdx.y;
    const float* h   = side ? ih   : uh;
    const float* loc = side ? iloc : uloc;
    __shared__ float locT[PAD][ASP];
    const int t = threadIdx.x;

    for (int i = t; i < ASP * PAD; i += 256) {
        int a = i >> 7, p = i & 127;
        locT[p][a] = loc[r * ASP * PAD + i];
    }
    __syncthreads();

    float* mult = Mult + (size_t)side * ROWS9 + r * 9;
    if (t < ASP) {
        float s = 0.f;
        for (int p = 0; p < PAD; p++) s += locT[p][t];
        mult[t] = s;
    } else if (t == ASP) {
        mult[8] = 128.0f;
    }

    const f4* h4 = (const f4*)(h + (size_t)r * PAD * HID) + t;
    f4 acc[9];
    #pragma unroll
    for (int a = 0; a < 9; a++) acc[a] = make_float4(0.f, 0.f, 0.f, 0.f);

    f4 buf[4];
    #pragma unroll
    for (int j = 0; j < 4; j++) buf[j] = h4[j * (HID / 4)];

    for (int p = 0; p < PAD; p += 4) {
        f4 nxt[4];
        if (p + 4 < PAD) {
            #pragma unroll
            for (int j = 0; j < 4; j++) nxt[j] = h4[(p + 4 + j) * (HID / 4)];
        }
        #pragma unroll
        for (int j = 0; j < 4; j++) {
            const f4* lrow = (const f4*)locT[p + j];
            f4 w0 = lrow[0], w1 = lrow[1];
            f4 v = buf[j];
            acc[8].x += v.x; acc[8].y += v.y; acc[8].z += v.z; acc[8].w += v.w;
            #define FMA_A(ai, ws) { acc[ai].x += (ws)*v.x; acc[ai].y += (ws)*v.y; \
                                    acc[ai].z += (ws)*v.z; acc[ai].w += (ws)*v.w; }
            FMA_A(0, w0.x) FMA_A(1, w0.y) FMA_A(2, w0.z) FMA_A(3, w0.w)
            FMA_A(4, w1.x) FMA_A(5, w1.y) FMA_A(6, w1.z) FMA_A(7, w1.w)
            #undef FMA_A
        }
        #pragma unroll
        for (int j = 0; j < 4; j++) buf[j] = nxt[j];
    }

    f4* out = (f4*)(Hcat + ((size_t)side * ROWS9 + (size_t)r * 9) * HID);
    #pragma unroll
    for (int a = 0; a < 9; a++) out[a * (HID / 4) + t] = acc[a];
}

// ---------------- K2: big GEMM, split-K, both sides in one launch ----------------------
// Part[z][m][n] = A[m, z*512 : (z+1)*512] @ B_side[...,n]
#define BM 64
#define BN 64
#define BKK 32
__global__ __launch_bounds__(256) void k_gemm2(
    const float* __restrict__ A, const float* __restrict__ Bu, const float* __restrict__ Bi,
    float* __restrict__ Part)
{
    __shared__ float As[BKK][BM];
    __shared__ float Bs[BKK][BN];
    const int t = threadIdx.x;
    const int m0 = blockIdx.x * BM, n0 = blockIdx.y * BN;
    const int side = (m0 >= ROWS9) ? 1 : 0;
    const float* B = side ? Bi : Bu;
    const int kbeg = blockIdx.z * (HID / KS);
    const int kend = kbeg + (HID / KS);
    const int tm = (t >> 4) << 2;
    const int tn = (t & 15) << 2;
    float c[4][4] = {};

    for (int k0 = kbeg; k0 < kend; k0 += BKK) {
        #pragma unroll
        for (int i = 0; i < 2; i++) {
            int e = t + i * 256;
            int row = e >> 3;
            int kq = (e & 7) << 2;
            f4 v = *(const f4*)&A[(size_t)(m0 + row) * HID + k0 + kq];
            As[kq + 0][row] = v.x; As[kq + 1][row] = v.y;
            As[kq + 2][row] = v.z; As[kq + 3][row] = v.w;
        }
        #pragma unroll
        for (int i = 0; i < 2; i++) {
            int e = t + i * 256;
            int row = e >> 4;
            int dq = (e & 15) << 2;
            *(f4*)&Bs[row][dq] = *(const f4*)&B[(size_t)(k0 + row) * DD + n0 + dq];
        }
        __syncthreads();
        #pragma unroll
        for (int k = 0; k < BKK; k++) {
            f4 a4 = *(const f4*)&As[k][tm];
            f4 b4 = *(const f4*)&Bs[k][tn];
            c[0][0] += a4.x * b4.x; c[0][1] += a4.x * b4.y; c[0][2] += a4.x * b4.z; c[0][3] += a4.x * b4.w;
            c[1][0] += a4.y * b4.x; c[1][1] += a4.y * b4.y; c[1][2] += a4.y * b4.z; c[1][3] += a4.y * b4.w;
            c[2][0] += a4.z * b4.x; c[2][1] += a4.z * b4.y; c[2][2] += a4.z * b4.z; c[2][3] += a4.z * b4.w;
            c[3][0] += a4.w * b4.x; c[3][1] += a4.w * b4.y; c[3][2] += a4.w * b4.z; c[3][3] += a4.w * b4.w;
        }
        __syncthreads();
    }

    float* P = Part + (size_t)blockIdx.z * MTOT * DD;
    #pragma unroll
    for (int i = 0; i < 4; i++) {
        *(f4*)&P[(size_t)(m0 + tm + i) * DD + n0 + tn] =
            make_float4(c[i][0], c[i][1], c[i][2], c[i][3]);
    }
}

// ---------------- K2f: sum split-K partials + mult*bias --------------------------------
__global__ __launch_bounds__(256) void k_gfin(
    const float* __restrict__ Part, const float* __restrict__ Mult,
    const float* __restrict__ bu_bias, const float* __restrict__ bi_bias,
    float* __restrict__ C)
{
    const size_t idx = (size_t)blockIdx.x * 256 + threadIdx.x;   // f4 index
    const f4* P4 = (const f4*)Part;
    f4 v = P4[idx];
    #pragma unroll
    for (int z = 1; z < KS; z++) {
        f4 w = P4[idx + (size_t)z * (MTOT * DD / 4)];
        v.x += w.x; v.y += w.y; v.z += w.z; v.w += w.w;
    }
    const int m = (int)(idx >> 6);          // DD/4 = 64 f4 per row
    const int n = ((int)idx & 63) << 2;
    const float* bias = (m >= ROWS9) ? bi_bias : bu_bias;
    float mm = Mult[m];
    v.x += mm * bias[n + 0];
    v.y += mm * bias[n + 1];
    v.z += mm * bias[n + 2];
    v.w += mm * bias[n + 3];
    ((f4*)C)[idx] = v;
}

// ---------------- K2b: small fp32 GEMM for cls projection ------------------------------
__global__ __launch_bounds__(256) void k_gemm(
    const float* __restrict__ A, const float* __restrict__ B,
    float* __restrict__ C, int M, int N, int K)
{
    __shared__ float As[BKK][BM];
    __shared__ float Bs[BKK][BN];
    const int t = threadIdx.x;
    const int m0 = blockIdx.x * BM, n0 = blockIdx.y * BN;
    const int tm = (t >> 4) << 2;
    const int tn = (t & 15) << 2;
    float c[4][4] = {};

    for (int k0 = 0; k0 < K; k0 += BKK) {
        #pragma unroll
        for (int i = 0; i < 2; i++) {
            int e = t + i * 256;
            int row = e >> 3;
            int kq = (e & 7) << 2;
            f4 v = *(const f4*)&A[(size_t)(m0 + row) * K + k0 + kq];
            As[kq + 0][row] = v.x; As[kq + 1][row] = v.y;
            As[kq + 2][row] = v.z; As[kq + 3][row] = v.w;
        }
        #pragma unroll
        for (int i = 0; i < 2; i++) {
            int e = t + i * 256;
            int row = e >> 4;
            int dq = (e & 15) << 2;
            *(f4*)&Bs[row][dq] = *(const f4*)&B[(size_t)(k0 + row) * N + n0 + dq];
        }
        __syncthreads();
        #pragma unroll
        for (int k = 0; k < BKK; k++) {
            f4 a4 = *(const f4*)&As[k][tm];
            f4 b4 = *(const f4*)&Bs[k][tn];
            c[0][0] += a4.x * b4.x; c[0][1] += a4.x * b4.y; c[0][2] += a4.x * b4.z; c[0][3] += a4.x * b4.w;
            c[1][0] += a4.y * b4.x; c[1][1] += a4.y * b4.y; c[1][2] += a4.y * b4.z; c[1][3] += a4.y * b4.w;
            c[2][0] += a4.z * b4.x; c[2][1] += a4.z * b4.y; c[2][2] += a4.z * b4.z; c[2][3] += a4.z * b4.w;
            c[3][0] += a4.w * b4.x; c[3][1] += a4.w * b4.y; c[3][2] += a4.w * b4.z; c[3][3] += a4.w * b4.w;
        }
        __syncthreads();
    }

    #pragma unroll
    for (int i = 0; i < 4; i++) {
        *(f4*)&C[(size_t)(m0 + tm + i) * N + n0 + tn] =
            make_float4(c[i][0], c[i][1], c[i][2], c[i][3]);
    }
}

// ---------------- K0: ea[side][a] = emb_aspect[a,:] . w_ex[side][256:512] -------------
__global__ __launch_bounds__(256) void k_ea(
    const float* __restrict__ emb, const float* __restrict__ wexu,
    const float* __restrict__ wexi, float* __restrict__ ea)
{
    int a = blockIdx.x, side = blockIdx.y;
    const float* w = (side ? wexi : wexu) + DD;
    __shared__ float red[256];
    float v = emb[a * DD + threadIdx.x] * w[threadIdx.x];
    float s = blockReduceSum(v, red);
    if (threadIdx.x == 0) ea[side * ASP + a] = s;
}

// ---------------- K3: attention scores (wave-shuffle reduce, 1 barrier) -----------------
__global__ __launch_bounds__(256) void k_scores(
    const float* __restrict__ AspAvg, const float* __restrict__ ClsRepr,
    const float* __restrict__ wexu, const float* __restrict__ wexi,
    const float* __restrict__ wimu, const float* __restrict__ wimi,
    const float* __restrict__ ea,
    float* __restrict__ sc_ex, float* __restrict__ sc_im)
{
    const int r = blockIdx.x, side = blockIdx.y, t = threadIdx.x;
    const float* wex = side ? wexi : wexu;
    const float* wim = side ? wimi : wimu;
    const float* rowbase = AspAvg + ((size_t)side * ROWS9 + (size_t)r * 9) * DD;
    __shared__ float sums[4][9];

    float wx = wex[t];
    float v[9];
    #pragma unroll
    for (int a = 0; a < 8; a++) v[a] = rowbase[a * DD + t] * wx;
    v[8] = ClsRepr[((size_t)side * TTL + r) * DD + t] * wim[t]
         + (rowbase[8 * DD + t] * (1.0f / 128.0f)) * wim[DD + t];

    #pragma unroll
    for (int off = 32; off > 0; off >>= 1) {
        #pragma unroll
        for (int a = 0; a < 9; a++) v[a] += __shfl_down(v[a], off, 64);
    }
    if ((t & 63) == 0) {
        int wv = t >> 6;
        #pragma unroll
        for (int a = 0; a < 9; a++) sums[wv][a] = v[a];
    }
    __syncthreads();
    if (t < 9) {
        float s = sums[0][t] + sums[1][t] + sums[2][t] + sums[3][t];
        if (t < 8) sc_ex[(side * TTL + r) * ASP + t] = tanhf(s + ea[side * ASP + t]);
        else       sc_im[side * TTL + r] = tanhf(s);
    }
}

// ---------------- K4: segment softmax attention (parallel over aspects) -----------------
__global__ __launch_bounds__(256) void k_segattn(
    const float* __restrict__ AspAvg, const float* __restrict__ ClsRepr,
    const float* __restrict__ sc_ex, const float* __restrict__ sc_im,
    const int* __restrict__ useg, const int* __restrict__ iseg,
    float* __restrict__ Expl, float* __restrict__ Impl)
{
    const int b = blockIdx.x, side = blockIdx.y, a = blockIdx.z, t = threadIdx.x;
    const int* seg = side ? iseg : useg;
    int lo = 0, hi = TTL;
    while (lo < hi) { int mid = (lo + hi) >> 1; if (seg[mid] < b) lo = mid + 1; else hi = mid; }
    const int start = lo;
    hi = TTL;
    while (lo < hi) { int mid = (lo + hi) >> 1; if (seg[mid] <= b) lo = mid + 1; else hi = mid; }
    const int end = lo;

    if (a < 8) {
        const float* scx = sc_ex + side * TTL * ASP;
        float m = -1e30f;
        for (int r = start; r < end; r++) m = fmaxf(m, scx[r * ASP + a]);
        float den = 0.f;
        for (int r = start; r < end; r++) den += expf(scx[r * ASP + a] - m);
        float acc = 0.f;
        for (int r = start; r < end; r++) {
            float w = expf(scx[r * ASP + a] - m) / den;
            acc += w * AspAvg[((size_t)side * ROWS9 + (size_t)r * 9 + a) * DD + t];
        }
        Expl[(((size_t)side * NB + b) * ASP + a) * DD + t] = acc;
    } else {
        const float* sci = sc_im + side * TTL;
        float m = -1e30f;
        for (int r = start; r < end; r++) m = fmaxf(m, sci[r]);
        float den = 0.f;
        for (int r = start; r < end; r++) den += expf(sci[r] - m);
        float a1 = 0.f, a2 = 0.f;
        for (int r = start; r < end; r++) {
            float w = expf(sci[r] - m) / den;
            a1 += w * ClsRepr[((size_t)side * TTL + r) * DD + t];
            a2 += w * (AspAvg[((size_t)side * ROWS9 + (size_t)r * 9 + 8) * DD + t] * (1.0f / 128.0f));
        }
        Impl[((size_t)side * NB + b) * (2 * DD) + t] = a1;
        Impl[((size_t)side * NB + b) * (2 * DD) + DD + t] = a2;
    }
}

// ---------------- K5: final heads ------------------------------------------------------
__global__ __launch_bounds__(256) void k_final(
    const float* __restrict__ Expl, const float* __restrict__ Impl,
    const float* __restrict__ imW1, const float* __restrict__ imb1, const float* __restrict__ imW2,
    const float* __restrict__ exW1, const float* __restrict__ exb1, const float* __restrict__ exW2,
    const float* __restrict__ bu, const float* __restrict__ bt, const float* __restrict__ gamma,
    const int* __restrict__ uid, const int* __restrict__ iid, float* __restrict__ out)
{
    const int b = blockIdx.x, t = threadIdx.x;
    __shared__ float catIm[4 * DD];
    __shared__ float catEx[2 * DD][ASP];
    __shared__ float red[256];

    catIm[t]       = Impl[(size_t)b * 512 + t];
    catIm[t + 256] = Impl[(size_t)b * 512 + t + 256];
    catIm[t + 512] = Impl[((size_t)NB + b) * 512 + t];
    catIm[t + 768] = Impl[((size_t)NB + b) * 512 + t + 256];
    #pragma unroll
    for (int a = 0; a < 8; a++) {
        catEx[t][a]       = Expl[((size_t)b * ASP + a) * DD + t];
        catEx[t + 256][a] = Expl[(((size_t)NB + b) * ASP + a) * DD + t];
    }
    __syncthreads();

    float g[8];
    #pragma unroll
    for (int a = 0; a < 8; a++) g[a] = gamma[a];

    float acc = imb1[t];
    for (int k = 0; k < 1024; k++) acc += catIm[k] * imW1[k * DD + t];
    float imh = fmaxf(acc, 0.f);
    float part = imh * imW2[t];

    float ex[8];
    #pragma unroll
    for (int a = 0; a < 8; a++) ex[a] = exb1[t];
    for (int k = 0; k < 512; k++) {
        float w = exW1[k * DD + t];
        #pragma unroll
        for (int a = 0; a < 8; a++) ex[a] += catEx[k][a] * w;
    }
    float exs = 0.f;
    #pragma unroll
    for (int a = 0; a < 8; a++) exs += fmaxf(ex[a], 0.f) * g[a];
    part += exs * exW2[t];

    float tot = blockReduceSum(part, red);
    if (t == 0) out[b] = bu[uid[b]] + bt[iid[b]] + tot;
}

// ---------------- launch ---------------------------------------------------------------
extern "C" void kernel_launch(void* const* d_in, const int* in_sizes, int n_in,
                              void* d_out, int out_size, void* d_ws, size_t ws_size,
                              hipStream_t stream) {
    const float* uh    = (const float*)d_in[0];
    const float* ih    = (const float*)d_in[1];
    const float* ucls  = (const float*)d_in[2];
    const float* icls  = (const float*)d_in[3];
    const float* uloc  = (const float*)d_in[4];
    const float* iloc  = (const float*)d_in[5];
    const float* Wuo   = (const float*)d_in[6];
    const float* buo   = (const float*)d_in[7];
    const float* Wio   = (const float*)d_in[8];
    const float* bio   = (const float*)d_in[9];
    const float* emb   = (const float*)d_in[10];
    const float* wexu  = (const float*)d_in[11];
    const float* wexi  = (const float*)d_in[12];
    const float* wimu  = (const float*)d_in[13];
    const float* wimi  = (const float*)d_in[14];
    const float* Wucls = (const float*)d_in[15];
    const float* Wicls = (const float*)d_in[16];
    const float* exW1  = (const float*)d_in[17];
    const float* exb1  = (const float*)d_in[18];
    const float* exW2  = (const float*)d_in[19];
    const float* imW1  = (const float*)d_in[20];
    const float* imb1  = (const float*)d_in[21];
    const float* imW2  = (const float*)d_in[22];
    const float* bu    = (const float*)d_in[23];
    const float* bt    = (const float*)d_in[24];
    const float* gam   = (const float*)d_in[25];
    const int*   useg  = (const int*)d_in[26];
    const int*   iseg  = (const int*)d_in[27];
    const int*   uid   = (const int*)d_in[28];
    const int*   iid   = (const int*)d_in[29];
    float* out = (float*)d_out;

    char* w = (char*)d_ws;
    auto carve = [&](size_t bytes) { void* p = (void*)w; w += (bytes + 255) & ~(size_t)255; return p; };
    float* Hcat    = (float*)carve(2ULL * ROWS9 * HID * 4);      // 37.7 MB
    float* Mult    = (float*)carve(2ULL * ROWS9 * 4);
    float* Part    = (float*)carve((size_t)KS * MTOT * DD * 4);  // 18.9 MB
    float* AspAvg  = (float*)carve(2ULL * ROWS9 * DD * 4);       // 9.4 MB
    float* ClsRepr = (float*)carve(2ULL * TTL * DD * 4);         // 1 MB
    float* sc_ex   = (float*)carve(2ULL * TTL * ASP * 4);
    float* sc_im   = (float*)carve(2ULL * TTL * 4);
    float* ea      = (float*)carve(2ULL * ASP * 4);
    float* Expl    = (float*)carve(2ULL * NB * ASP * DD * 4);    // 2 MB
    float* Impl    = (float*)carve(2ULL * NB * 2 * DD * 4);
    (void)ws_size; (void)n_in; (void)in_sizes; (void)out_size;

    // K1: stream 512 MB of hidden states, contract over PAD (4-deep pipelined)
    k_reduce<<<dim3(TTL, 2), 256, 0, stream>>>(uh, ih, uloc, iloc, Hcat, Mult);

    // K2: (9216 x 1024) @ (1024 x 256), both sides, split-K=2
    k_gemm2<<<dim3(MTOT / BM, DD / BN, KS), 256, 0, stream>>>(Hcat, Wuo, Wio, Part);
    k_gfin<<<dim3(MTOT * DD / 4 / 256), 256, 0, stream>>>(Part, Mult, buo, bio, AspAvg);

    // K2b: cls projection per side: (512 x 256) @ (256 x 256)
    for (int s = 0; s < 2; s++) {
        k_gemm<<<dim3(TTL / BM, DD / BN), 256, 0, stream>>>(
            s ? icls : ucls, s ? Wicls : Wucls,
            ClsRepr + (size_t)s * TTL * DD, TTL, DD, DD);
    }

    k_ea<<<dim3(ASP, 2), 256, 0, stream>>>(emb, wexu, wexi, ea);
    k_scores<<<dim3(TTL, 2), 256, 0, stream>>>(AspAvg, ClsRepr, wexu, wexi, wimu, wimi, ea, sc_ex, sc_im);
    k_segattn<<<dim3(NB, 2, 9), 256, 0, stream>>>(AspAvg, ClsRepr, sc_ex, sc_im, useg, iseg, Expl, Impl);
    k_final<<<dim3(NB), 256, 0, stream>>>(Expl, Impl, imW1, imb1, imW2,
                                          exW1, exb1, exW2, bu, bt, gam, uid, iid, out);
}